// Round 1
// baseline (119.350 us; speedup 1.0000x reference)
//
#include <hip/hip_runtime.h>

#define NATOMS 16
#define AEV_LEN 384   // 64 radial + 320 angular

// One block per molecule. 256 threads = one (i,j) pair per thread.
__global__ __launch_bounds__(256, 2) void aev_kernel(const int* __restrict__ species,
                                                     const float* __restrict__ coords,
                                                     float* __restrict__ out,
                                                     int nmol) {
    const int b = blockIdx.x;
    const int t = threadIdx.x;

    __shared__ float sxx[NATOMS], syy[NATOMS], szz[NATOMS];
    __shared__ int   ssp[NATOMS];
    __shared__ float sd[NATOMS][NATOMS];
    __shared__ float sfca[NATOMS][NATOMS];
    __shared__ float acc[NATOMS][AEV_LEN];

    if (t < NATOMS) {
        int sp = species[b * NATOMS + t];
        ssp[t] = sp;
        sxx[t] = coords[(b * NATOMS + t) * 3 + 0];
        syy[t] = coords[(b * NATOMS + t) * 3 + 1];
        szz[t] = coords[(b * NATOMS + t) * 3 + 2];
        // first output: species, written as float values (single-dtype out buffer)
        out[b * NATOMS + t] = (float)sp;
    }
    // zero accumulators
    float* accf = &acc[0][0];
    for (int idx = t; idx < NATOMS * AEV_LEN; idx += 256) accf[idx] = 0.0f;
    __syncthreads();

    const int i = t >> 4;
    const int j = t & 15;
    const int si = ssp[i];
    const int sj = ssp[j];

    // diff[i][j] = c_i - c_j (reference convention)
    const float dx = sxx[i] - sxx[j];
    const float dy = syy[i] - syy[j];
    const float dz = szz[i] - szz[j];
    const float d2 = dx * dx + dy * dy + dz * dz;
    const bool pv = (i != j) && (si >= 0) && (sj >= 0);
    const float d = sqrtf(pv ? d2 : 1.0f);   // "safe" distance = 1 for invalid pairs
    sd[i][j] = d;

    const float PI = 3.14159265358979323846f;
    const float fca = (pv && d <= 3.5f) ? (0.5f * cosf(PI * d * (1.0f / 3.5f)) + 0.5f) : 0.0f;
    sfca[i][j] = fca;
    const float fcr = (pv && d <= 5.2f) ? (0.5f * cosf(PI * d * (1.0f / 5.2f)) + 0.5f) : 0.0f;

    // ---- radial AEV ----
    if (fcr > 0.0f) {
        float* dst = &acc[i][sj * 16];
        #pragma unroll
        for (int r = 0; r < 16; ++r) {
            float sh = 0.9f + 0.26875f * (float)r;
            float e = d - sh;
            atomicAdd(&dst[r], 0.25f * __expf(-16.0f * e * e) * fcr);
        }
    }
    __syncthreads();

    // ---- angular AEV ----
    // cos/sin of ShfZ = (2z+1)*pi/16
    const float CZ0 = 0.980785280403230f, CZ1 = 0.831469612302545f,
                CZ2 = 0.555570233019602f, CZ3 = 0.195090322016128f;
    const float SZ0 = 0.195090322016128f, SZ1 = 0.555570233019602f,
                SZ2 = 0.831469612302545f, SZ3 = 0.980785280403230f;
    const float CZ[8] = { CZ0,  CZ1,  CZ2,  CZ3, -CZ3, -CZ2, -CZ1, -CZ0};
    const float SZ[8] = { SZ0,  SZ1,  SZ2,  SZ3,  SZ3,  SZ2,  SZ1,  SZ0};

    const float fca_ij = fca;
    const float d_ij = d;

    if (sj >= 0 && fca_ij > 0.0f) {
        for (int skt = 0; skt < 4; ++skt) {   // target species of k (block-uniform inner skip)
            float a32[32];
            #pragma unroll
            for (int f = 0; f < 32; ++f) a32[f] = 0.0f;
            bool any = false;

            for (int k = 0; k < NATOMS; ++k) {
                if (ssp[k] != skt) continue;          // block-uniform branch
                float fca_ik = sfca[i][k];
                float tri = (k != j) ? fca_ij * fca_ik : 0.0f;
                if (tri > 0.0f) {
                    any = true;
                    float ex = sxx[i] - sxx[k];
                    float ey = syy[i] - syy[k];
                    float ez = szz[i] - szz[k];
                    float dot = dx * ex + dy * ey + dz * ez;
                    float d_ik = sd[i][k];
                    float ca = 0.95f * dot / (d_ij * d_ik);
                    ca = fminf(0.95f, fmaxf(-0.95f, ca));
                    float sa = sqrtf(1.0f - ca * ca);  // sin(arccos(ca)) >= 0
                    float davg = 0.5f * (d_ij + d_ik);
                    float tf2[4];
                    #pragma unroll
                    for (int a = 0; a < 4; ++a) {
                        float e = davg - (0.9f + 0.65f * (float)a);
                        tf2[a] = tri * __expf(-8.0f * e * e);
                    }
                    #pragma unroll
                    for (int z = 0; z < 8; ++z) {
                        // cos(ang - shfz) = ca*cos(shfz) + sa*sin(shfz)
                        float c1 = 0.5f * (1.0f + ca * CZ[z] + sa * SZ[z]);
                        float p = c1 * c1;   // ^2
                        p *= p;              // ^4
                        p *= p;              // ^8
                        p *= p;              // ^16
                        p *= p;              // ^32
                        #pragma unroll
                        for (int a = 0; a < 4; ++a)
                            a32[a * 8 + z] = fmaf(tf2[a], p, a32[a * 8 + z]);
                    }
                }
            }

            if (any) {
                // unordered pair index (torchani triu order), computed arithmetically
                int lo = sj < skt ? sj : skt;
                int hi = sj < skt ? skt : sj;
                int p = lo * 4 + hi - ((lo * (lo + 1)) >> 1);
                float* dst = &acc[i][64 + p * 32];
                #pragma unroll
                for (int f = 0; f < 32; ++f) atomicAdd(&dst[f], a32[f]);
            }
        }
    }
    __syncthreads();

    // ---- write out: [nmol*16] species (already written) then [nmol,16,384] AEV ----
    float* oa = out + (size_t)nmol * NATOMS + (size_t)b * (NATOMS * AEV_LEN);
    for (int idx = t; idx < NATOMS * AEV_LEN; idx += 256) oa[idx] = accf[idx];
}

extern "C" void kernel_launch(void* const* d_in, const int* in_sizes, int n_in,
                              void* d_out, int out_size, void* d_ws, size_t ws_size,
                              hipStream_t stream) {
    const int*   species = (const int*)d_in[0];
    const float* coords  = (const float*)d_in[1];
    float*       out     = (float*)d_out;
    int nmol = in_sizes[0] / NATOMS;   // 512
    aev_kernel<<<nmol, 256, 0, stream>>>(species, coords, out, nmol);
}

// Round 5
// 70.010 us; speedup vs baseline: 1.7047x; 1.7047x over previous
//
#include <hip/hip_runtime.h>

#define NATOMS 16

// Block = (molecule, pair-of-atoms): grid = nmol*8, 128 threads = 2 waves.
// Wave w handles center atom i = (blockIdx.x&7)*2 + w.
__global__ __launch_bounds__(128, 8) void aev_kernel(const int* __restrict__ species,
                                                     const float* __restrict__ coords,
                                                     float* __restrict__ out,
                                                     int nmol) {
    const int t = threadIdx.x;
    const int w = t >> 6;        // wave 0/1
    const int l = t & 63;        // lane in wave
    const int b = blockIdx.x >> 3;
    const int q = blockIdx.x & 7;
    const int i = q * 2 + w;     // center atom for this wave

    __shared__ float sx[16], sy[16], sz[16];
    __shared__ int   ssp[16];
    __shared__ float sCZh[8], sSZh[8], sGa[4];
    __shared__ float dX[2][16], dY[2][16], dZ[2][16];
    __shared__ float sD[2][16], sRinv[2][16], sFca[2][16];
    __shared__ float rad[2][16][17];                 // padded: conflict-free
    __shared__ int   hist[2][10], sBase[2][10], sCur[2][10];
    __shared__ float4 ebuf[2][120];                  // (ca, sa, t0=2*fcaj*fcak*exp(-8(davg-.9)^2), r1)

    // ---- setup ----
    if (t < 16) {
        int sp = species[b * 16 + t];
        ssp[t] = sp;
        sx[t] = coords[(b * 16 + t) * 3 + 0];
        sy[t] = coords[(b * 16 + t) * 3 + 1];
        sz[t] = coords[(b * 16 + t) * 3 + 2];
        if (q == 0) out[b * 16 + t] = (float)sp;     // species output as float
    }
    if (t < 8) {
        float ang = (2.f * (float)t + 1.f) * 0.19634954084936207f;  // (2z+1)*pi/16
        sCZh[t] = 0.5f * __cosf(ang);
        sSZh[t] = 0.5f * __sinf(ang);
    }
    if (t < 4) {
        int tri = (t * (t - 1)) >> 1;                // {0,0,1,3}
        sGa[t] = __expf(-6.76f * (float)tri);        // g = exp(-2*8*0.65^2)
    }
    if (l < 10) hist[w][l] = 0;
    __syncthreads();

    const int spi = ssp[i];

    // ---- phase 1: per-j pair quantities + radial terms (lanes 0..15) ----
    if (l < 16) {
        int jj = l;
        int spj = ssp[jj];
        float dx = sx[i] - sx[jj];
        float dy = sy[i] - sy[jj];
        float dz = sz[i] - sz[jj];
        bool pv = (jj != i) && (spi >= 0) && (spj >= 0);
        float d2 = dx * dx + dy * dy + dz * dz;
        float d = sqrtf(pv ? d2 : 1.0f);
        float rinv = 1.0f / d;
        float fca = (pv && d <= 3.5f) ? (0.5f * __cosf(d * 0.8975979010256552f) + 0.5f) : 0.0f;
        float fcr = (pv && d <= 5.2f) ? (0.5f * __cosf(d * 0.6041515809446141f) + 0.5f) : 0.0f;
        dX[w][jj] = dx; dY[w][jj] = dy; dZ[w][jj] = dz;
        sD[w][jj] = d; sRinv[w][jj] = rinv; sFca[w][jj] = fca;
        float fcr4 = 0.25f * fcr;
        #pragma unroll
        for (int r = 0; r < 16; ++r) {
            float e = d - (0.9f + 0.26875f * (float)r);
            rad[w][jj][r] = fcr4 * __expf(-16.0f * e * e);
        }
    }
    __syncthreads();

    // ---- phase 2a: histogram of valid triples by species-pair ----
    // slots s in [0,120): unordered (j<k); decode via inverse triangular number
    int j1 = -1, k1 = -1, p1 = -1, j2 = -1, k2 = -1, p2 = -1;
    {
        int s = l;
        float sq = sqrtf((float)(961 - 8 * s));
        int j = (int)floorf((31.0f - sq) * 0.5f);
        j = j < 0 ? 0 : (j > 14 ? 14 : j);
        int off = (j * (31 - j)) >> 1;
        if (s < off) { --j; off = (j * (31 - j)) >> 1; }
        else { int off2 = ((j + 1) * (30 - j)) >> 1; if (s >= off2) { ++j; off = off2; } }
        int k = j + 1 + (s - off);
        if (sFca[w][j] > 0.f && sFca[w][k] > 0.f) {
            int s1 = ssp[j], s2 = ssp[k];
            int lo = s1 < s2 ? s1 : s2, hi = s1 < s2 ? s2 : s1;
            p1 = lo * 4 + hi - ((lo * (lo + 1)) >> 1);
            j1 = j; k1 = k;
            atomicAdd(&hist[w][p1], 1);
        }
    }
    if (l + 64 < 120) {
        int s = l + 64;
        float sq = sqrtf((float)(961 - 8 * s));
        int j = (int)floorf((31.0f - sq) * 0.5f);
        j = j < 0 ? 0 : (j > 14 ? 14 : j);
        int off = (j * (31 - j)) >> 1;
        if (s < off) { --j; off = (j * (31 - j)) >> 1; }
        else { int off2 = ((j + 1) * (30 - j)) >> 1; if (s >= off2) { ++j; off = off2; } }
        int k = j + 1 + (s - off);
        if (sFca[w][j] > 0.f && sFca[w][k] > 0.f) {
            int s1 = ssp[j], s2 = ssp[k];
            int lo = s1 < s2 ? s1 : s2, hi = s1 < s2 ? s2 : s1;
            p2 = lo * 4 + hi - ((lo * (lo + 1)) >> 1);
            j2 = j; k2 = k;
            atomicAdd(&hist[w][p2], 1);
        }
    }
    __syncthreads();

    // ---- phase 2b: exclusive prefix over 10 buckets ----
    if (l < 10) {
        int sum = 0;
        for (int qq = 0; qq < l; ++qq) sum += hist[w][qq];
        sBase[w][l] = sum;
        sCur[w][l] = sum;
    }
    __syncthreads();

    // ---- phase 2c: fill buckets with (ca, sa, t0, r1) ----
    #pragma unroll
    for (int slot = 0; slot < 2; ++slot) {
        int jj = slot == 0 ? j1 : j2;
        int kk = slot == 0 ? k1 : k2;
        int pp = slot == 0 ? p1 : p2;
        if (jj >= 0) {
            float fj = sFca[w][jj], fk = sFca[w][kk];
            float dot = dX[w][jj] * dX[w][kk] + dY[w][jj] * dY[w][kk] + dZ[w][jj] * dZ[w][kk];
            float ca = 0.95f * dot * sRinv[w][jj] * sRinv[w][kk];
            ca = fminf(0.95f, fmaxf(-0.95f, ca));
            float sa = sqrtf(1.0f - ca * ca);
            float davg = 0.5f * (sD[w][jj] + sD[w][kk]);
            float e0 = davg - 0.9f;
            float t0 = 2.0f * fj * fk * __expf(-8.0f * e0 * e0);
            float r1 = __expf(10.4f * davg - 12.74f);
            int idx = atomicAdd(&sCur[w][pp], 1);
            ebuf[w][idx] = make_float4(ca, sa, t0, r1);
        }
    }
    __syncthreads();

    // ---- phase B: angular gather, lane = (p-half, f), f = a*8+z ----
    float* base_o = out + (size_t)nmol * 16 + (size_t)(b * 16 + i) * 384;
    {
        int f = l & 31;
        int z = f & 7;
        int a = f >> 3;
        float czh = sCZh[z];
        float szh = sSZh[z];
        float ga = sGa[a];
        int a1 = a & 1, a2 = a & 2;
        #pragma unroll
        for (int pp = 0; pp < 5; ++pp) {
            int p = pp * 2 + (l >> 5);
            int st = sBase[w][p];
            int n = hist[w][p];
            float acc = 0.0f;
            for (int e = 0; e < n; ++e) {
                float4 v = ebuf[w][st + e];
                float c1 = fmaf(czh, v.x, fmaf(szh, v.y, 0.5f));
                float c2 = c1 * c1;
                float c4 = c2 * c2;
                float c8 = c4 * c4;
                float c16 = c8 * c8;
                float c32 = c16 * c16;
                float tt = v.z;
                float rsq = v.w * v.w;
                tt = a1 ? tt * v.w : tt;
                tt = a2 ? tt * rsq : tt;
                acc = fmaf(tt, c32, acc);
            }
            base_o[64 + p * 32 + f] = acc * ga;
        }
    }

    // ---- phase R: radial gather, lane = s*16+r ----
    {
        int s_ = l >> 4, r_ = l & 15;
        float rv = 0.0f;
        #pragma unroll
        for (int jj = 0; jj < 16; ++jj)
            rv += (ssp[jj] == s_) ? rad[w][jj][r_] : 0.0f;
        base_o[l] = rv;
    }
}

extern "C" void kernel_launch(void* const* d_in, const int* in_sizes, int n_in,
                              void* d_out, int out_size, void* d_ws, size_t ws_size,
                              hipStream_t stream) {
    const int*   species = (const int*)d_in[0];
    const float* coords  = (const float*)d_in[1];
    float*       out     = (float*)d_out;
    int nmol = in_sizes[0] / NATOMS;   // 512
    aev_kernel<<<nmol * 8, 128, 0, stream>>>(species, coords, out, nmol);
}